// Round 2
// baseline (100.300 us; speedup 1.0000x reference)
//
#include <hip/hip_runtime.h>
#include <hip/hip_bf16.h>

#define BB 4
#define SS 1024
#define DDIM 64

typedef __attribute__((ext_vector_type(4))) float f32x4;
typedef __attribute__((ext_vector_type(8))) short bf16x8;

__device__ __forceinline__ float fast_exp2(float x) { return __builtin_amdgcn_exp2f(x); }
__device__ __forceinline__ float fast_rcp(float x)  { return __builtin_amdgcn_rcpf(x); }

// float -> bf16 bits, round-to-nearest-even (finite inputs only)
__device__ __forceinline__ unsigned short f2bf(float f) {
    unsigned int u = __builtin_bit_cast(unsigned int, f);
    u += 0x7fffu + ((u >> 16) & 1u);
    return (unsigned short)(u >> 16);
}

// ---------------------------------------------------------------------------
// K1: projections. q = x@Wq^T, k = x@Wk^T + bk, v = x@Wv^T.
// Writes q32,k32 (f32 [B,S,D]), xs = x * 2*log2e (f32), and xT,vT transposed
// bf16 [B,D,S] for MFMA B-fragments in K3.
// grid 128, block 256: 32 rows/block, 8 d's per thread (d = (t&7) + 8*jd).
// ---------------------------------------------------------------------------
__global__ __launch_bounds__(256) void k_proj(
    const float* __restrict__ x, const float* __restrict__ Wq,
    const float* __restrict__ Wk, const float* __restrict__ bkv,
    const float* __restrict__ Wv,
    float* __restrict__ q32, float* __restrict__ k32, float* __restrict__ xs,
    unsigned short* __restrict__ xT, unsigned short* __restrict__ vT)
{
    __shared__ float wq[64*68], wk[64*68], wv[64*68];
    const int t = threadIdx.x;
    for (int i = t; i < 4096; i += 256) {
        const int d = i >> 6, e = i & 63;
        wq[d*68+e] = Wq[i]; wk[d*68+e] = Wk[i]; wv[d*68+e] = Wv[i];
    }
    __syncthreads();
    const int row  = blockIdx.x * 32 + (t >> 3);
    const int b    = row >> 10, srow = row & 1023;
    const int dl   = t & 7;
    float xr[64];
    const float* xp = x + (size_t)row * 64;
    #pragma unroll
    for (int i = 0; i < 16; ++i) {
        f32x4 v = *(const f32x4*)(xp + i*4);
        xr[i*4+0]=v[0]; xr[i*4+1]=v[1]; xr[i*4+2]=v[2]; xr[i*4+3]=v[3];
    }
    const float C2 = 2.8853900817779268f;   // 2*log2(e)
    #pragma unroll
    for (int jd = 0; jd < 8; ++jd) {
        const int d = dl + jd*8;
        const float* pq = wq + d*68;
        const float* pk = wk + d*68;
        const float* pv = wv + d*68;
        float aq = 0.f, ak = 0.f, av = 0.f;
        #pragma unroll
        for (int e4 = 0; e4 < 16; ++e4) {
            f32x4 q4 = *(const f32x4*)(pq + e4*4);
            f32x4 k4 = *(const f32x4*)(pk + e4*4);
            f32x4 v4 = *(const f32x4*)(pv + e4*4);
            #pragma unroll
            for (int u = 0; u < 4; ++u) {
                aq += xr[e4*4+u]*q4[u];
                ak += xr[e4*4+u]*k4[u];
                av += xr[e4*4+u]*v4[u];
            }
        }
        ak += bkv[d];
        q32[(size_t)row*64 + d] = aq;
        k32[(size_t)row*64 + d] = ak;
        xs [(size_t)row*64 + d] = xr[d]*C2;
        xT[((size_t)b*64 + d)*1024 + srow] = f2bf(xr[d]);
        vT[((size_t)b*64 + d)*1024 + srow] = f2bf(av);
    }
}

// ---------------------------------------------------------------------------
// K2: raw scores for all 3 branches over the causal lower-triangle,
// 32(q) x 64(k) tiles. No masking here (K3 masks on read).
//   s1 = dot(x_q,x_k)           (computed from xs with 1/c^2 correction)
//   s2 = dot(q,k) * 0.125 * attn_scale
//   s3 = sum_d tanh(x_q+x_k) = 64 - 2*sum_d 1/(exp2(xs_q+xs_k)+1)
// grid 1088 = B * tri(16) * 2 half-tiles, block 256.
// ---------------------------------------------------------------------------
__global__ __launch_bounds__(256) void k_scores(
    const float* __restrict__ xs, const float* __restrict__ q32,
    const float* __restrict__ k32, const float* __restrict__ attn_scale,
    float* __restrict__ sc)
{
    __shared__ float sxq[32*68], sq[32*68], sxk[64*68], sk[64*68];
    const int t = threadIdx.x;
    const int idx = blockIdx.x;
    const int b = idx / 272;
    const int rem = idx % 272;
    const int ti = rem >> 1, half = rem & 1;
    int qt = 0;
    while ((qt+1)*(qt+2)/2 <= ti) ++qt;
    const int kt = ti - qt*(qt+1)/2;
    const int q0 = qt*64 + half*32, k0 = kt*64;

    {   // stage q-side (32 rows x 64)
        const int row = t >> 3, seg = (t & 7) * 8;
        const float* gx = xs  + ((size_t)b*SS + q0 + row)*64 + seg;
        const float* gq = q32 + ((size_t)b*SS + q0 + row)*64 + seg;
        f32x4* dx = (f32x4*)(sxq + row*68 + seg);
        f32x4* dq = (f32x4*)(sq  + row*68 + seg);
        dx[0] = *(const f32x4*)(gx);   dx[1] = *(const f32x4*)(gx+4);
        dq[0] = *(const f32x4*)(gq);   dq[1] = *(const f32x4*)(gq+4);
    }
    {   // stage k-side (64 rows x 64)
        const int row = t >> 2, seg = (t & 3) * 16;
        const float* gx = xs  + ((size_t)b*SS + k0 + row)*64 + seg;
        const float* gk = k32 + ((size_t)b*SS + k0 + row)*64 + seg;
        f32x4* dx = (f32x4*)(sxk + row*68 + seg);
        f32x4* dk = (f32x4*)(sk  + row*68 + seg);
        #pragma unroll
        for (int i = 0; i < 4; ++i) {
            dx[i] = *(const f32x4*)(gx + i*4);
            dk[i] = *(const f32x4*)(gk + i*4);
        }
    }
    __syncthreads();

    const int qp = t >> 4;        // rows qp*2 + i
    const int kb = t & 15;        // cols kb + 16*j
    float a1[2][4] = {}, a2[2][4] = {}, ar[2][4] = {};
    #pragma unroll 4
    for (int d0 = 0; d0 < 64; d0 += 4) {
        f32x4 xq[2], qq[2], xk[4], kk[4];
        #pragma unroll
        for (int i = 0; i < 2; ++i) {
            xq[i] = *(const f32x4*)(sxq + (qp*2+i)*68 + d0);
            qq[i] = *(const f32x4*)(sq  + (qp*2+i)*68 + d0);
        }
        #pragma unroll
        for (int j = 0; j < 4; ++j) {
            xk[j] = *(const f32x4*)(sxk + (kb + 16*j)*68 + d0);
            kk[j] = *(const f32x4*)(sk  + (kb + 16*j)*68 + d0);
        }
        #pragma unroll
        for (int i = 0; i < 2; ++i)
        #pragma unroll
        for (int j = 0; j < 4; ++j)
        #pragma unroll
        for (int dd = 0; dd < 4; ++dd) {
            a1[i][j] += xq[i][dd]*xk[j][dd];
            a2[i][j] += qq[i][dd]*kk[j][dd];
            float e = fast_exp2(xq[i][dd] + xk[j][dd]);
            ar[i][j] += fast_rcp(e + 1.0f);
        }
    }
    const float C2 = 2.8853900817779268f;
    const float inv_c2 = 1.0f/(C2*C2);
    const float s2s = 0.125f * attn_scale[0];
    const size_t plane = (size_t)SS*SS;
    float* p1 = sc + ((size_t)0*BB + b)*plane;
    float* p2 = sc + ((size_t)1*BB + b)*plane;
    float* p3 = sc + ((size_t)2*BB + b)*plane;
    #pragma unroll
    for (int i = 0; i < 2; ++i) {
        const int qrow = q0 + qp*2 + i;
        const size_t rb = (size_t)qrow*SS + k0 + kb;
        #pragma unroll
        for (int j = 0; j < 4; ++j) {
            p1[rb + 16*j] = a1[i][j]*inv_c2;
            p2[rb + 16*j] = a2[i][j]*s2s;
            p3[rb + 16*j] = 64.0f - 2.0f*ar[i][j];
        }
    }
}

// ---------------------------------------------------------------------------
// K3: per (b, 16-row q-tile): for each branch, row-max pass, then chunked
// exp -> P(bf16, LDS) -> MFMA P*V with V from pre-transposed xT/vT.
// Unnormalized accumulation; divide by row-sum l at the end; blend with
// normalized attn_w; write f32 output.
// grid 256 = B*64, block 256 (4 waves; wave w owns d-block w*16).
// ---------------------------------------------------------------------------
__global__ __launch_bounds__(256) void k_out(
    const float* __restrict__ sc, const unsigned short* __restrict__ xT,
    const unsigned short* __restrict__ vT, const float* __restrict__ attn_w,
    float* __restrict__ out)
{
    __shared__ unsigned short Pl[16*72];
    __shared__ unsigned short Vl[64*72];
    __shared__ float l_arr[16];
    const int t = threadIdx.x;
    const int b = blockIdx.x >> 6, qt = blockIdx.x & 63;
    const int q0 = qt*16, KE = q0 + 16;
    const int row16 = t >> 4, col16 = t & 15;
    const int q = q0 + row16;
    const int wv = t >> 6, lane = t & 63;
    const float aw0 = attn_w[0], aw1 = attn_w[1], aw2 = attn_w[2];
    const float wsum = aw0 + aw1 + aw2;
    const float wbr[3] = {aw0/wsum, aw1/wsum, aw2/wsum};
    const float LOG2E = 1.4426950408889634f;
    f32x4 oacc = {0.f,0.f,0.f,0.f};

    for (int br = 0; br < 3; ++br) {
        const float* sp = sc + ((size_t)br*BB + b)*((size_t)SS*SS) + (size_t)q*SS;
        const unsigned short* Vt = ((br == 1) ? vT : xT) + (size_t)b*64*1024;

        // pass 1: causal row max
        float m = -3.0e38f;
        for (int k = col16*4; k < KE; k += 64) {
            f32x4 s4 = *(const f32x4*)(sp + k);
            #pragma unroll
            for (int j = 0; j < 4; ++j)
                if (k + j <= q) m = fmaxf(m, s4[j]);
        }
        #pragma unroll
        for (int off = 8; off >= 1; off >>= 1)
            m = fmaxf(m, __shfl_xor(m, off, 64));

        // pass 2: exp + PV
        float lsum = 0.f;
        f32x4 acc = {0.f,0.f,0.f,0.f};
        for (int kc = 0; kc < KE; kc += 64) {
            __syncthreads();   // previous chunk's MFMA reads done
            {   // P chunk [16][64] bf16 (unnormalized, masked)
                const int k = kc + col16*4;
                f32x4 s4 = *(const f32x4*)(sp + k);
                float e0 = (k+0 <= q) ? fast_exp2((s4[0]-m)*LOG2E) : 0.f;
                float e1 = (k+1 <= q) ? fast_exp2((s4[1]-m)*LOG2E) : 0.f;
                float e2 = (k+2 <= q) ? fast_exp2((s4[2]-m)*LOG2E) : 0.f;
                float e3 = (k+3 <= q) ? fast_exp2((s4[3]-m)*LOG2E) : 0.f;
                lsum += e0+e1+e2+e3;
                unsigned long long pk =
                    (unsigned long long)f2bf(e0)
                  | ((unsigned long long)f2bf(e1) << 16)
                  | ((unsigned long long)f2bf(e2) << 32)
                  | ((unsigned long long)f2bf(e3) << 48);
                *(unsigned long long*)(Pl + row16*72 + col16*4) = pk;
            }
            {   // V chunk [64][64] bf16 from transposed global
                const int dV = t >> 2, seg = (t & 3) * 16;
                const f32x4* src = (const f32x4*)(Vt + (size_t)dV*1024 + kc + seg);
                f32x4* dst = (f32x4*)(Vl + dV*72 + seg);
                dst[0] = src[0]; dst[1] = src[1];
            }
            __syncthreads();
            const int d0 = wv*16;
            #pragma unroll
            for (int ks = 0; ks < 2; ++ks) {
                bf16x8 af = *(const bf16x8*)(Pl + (lane & 15)*72 + ks*32 + (lane >> 4)*8);
                bf16x8 bf = *(const bf16x8*)(Vl + (d0 + (lane & 15))*72 + ks*32 + (lane >> 4)*8);
                acc = __builtin_amdgcn_mfma_f32_16x16x32_bf16(af, bf, acc, 0, 0, 0);
            }
        }
        // row-sum reduce and broadcast via LDS (acc rows != pass rows)
        #pragma unroll
        for (int off = 8; off >= 1; off >>= 1)
            lsum += __shfl_xor(lsum, off, 64);
        if (col16 == 0) l_arr[row16] = lsum;
        __syncthreads();
        #pragma unroll
        for (int i = 0; i < 4; ++i) {
            float li = l_arr[(lane >> 4)*4 + i];
            oacc[i] += wbr[br] * acc[i] * fast_rcp(li);
        }
    }
    #pragma unroll
    for (int i = 0; i < 4; ++i) {
        const int qrow = q0 + (lane >> 4)*4 + i;
        const int d = wv*16 + (lane & 15);
        out[((size_t)b*SS + qrow)*64 + d] = oacc[i];
    }
}

extern "C" void kernel_launch(void* const* d_in, const int* in_sizes, int n_in,
                              void* d_out, int out_size, void* d_ws, size_t ws_size,
                              hipStream_t stream) {
    (void)in_sizes; (void)n_in; (void)out_size; (void)ws_size;
    const float* x          = (const float*)d_in[0];
    const float* Wq         = (const float*)d_in[1];
    const float* Wk         = (const float*)d_in[2];
    const float* bk         = (const float*)d_in[3];
    const float* Wv         = (const float*)d_in[4];
    const float* attn_w     = (const float*)d_in[5];
    const float* attn_scale = (const float*)d_in[6];
    float* out              = (float*)d_out;            // f32 output (ref is f32)

    // workspace carve-up (~52 MB)
    float* sc  = (float*)d_ws;                          // [3][B][S][S] f32
    float* q32 = sc + (size_t)3*BB*SS*SS;
    float* k32 = q32 + (size_t)BB*SS*DDIM;
    float* xs  = k32 + (size_t)BB*SS*DDIM;
    unsigned short* xT = (unsigned short*)(xs + (size_t)BB*SS*DDIM); // [B][D][S] bf16
    unsigned short* vT = xT + (size_t)BB*DDIM*SS;

    k_proj  <<<128, 256, 0, stream>>>(x, Wq, Wk, bk, Wv, q32, k32, xs, xT, vT);
    k_scores<<<1088, 256, 0, stream>>>(xs, q32, k32, attn_scale, sc);
    k_out   <<<256, 256, 0, stream>>>(sc, xT, vT, attn_w, out);
}

// Round 3
// 86.226 us; speedup vs baseline: 1.1632x; 1.1632x over previous
//
#include <hip/hip_runtime.h>
#include <hip/hip_bf16.h>

#define BB 4
#define SS 1024
#define DDIM 64

typedef __attribute__((ext_vector_type(4))) float f32x4;
typedef __attribute__((ext_vector_type(8))) short bf16x8;

__device__ __forceinline__ float fast_exp2(float x) { return __builtin_amdgcn_exp2f(x); }
__device__ __forceinline__ float fast_rcp(float x)  { return __builtin_amdgcn_rcpf(x); }

// float -> bf16 bits, round-to-nearest-even (finite inputs only)
__device__ __forceinline__ unsigned short f2bf(float f) {
    unsigned int u = __builtin_bit_cast(unsigned int, f);
    u += 0x7fffu + ((u >> 16) & 1u);
    return (unsigned short)(u >> 16);
}

// ---------------------------------------------------------------------------
// K1: projections. q=x@Wq^T, k=x@Wk^T+bk, v=x@Wv^T.
// Writes q32,k32 (f32 [B,S,D]), exf = exp2(2*log2e*x) (f32, for the tanh
// factorization in k_s3), and xT,vT transposed bf16 [B,D,S] for k_out2.
// ---------------------------------------------------------------------------
__global__ __launch_bounds__(256) void k_proj(
    const float* __restrict__ x, const float* __restrict__ Wq,
    const float* __restrict__ Wk, const float* __restrict__ bkv,
    const float* __restrict__ Wv,
    float* __restrict__ q32, float* __restrict__ k32, float* __restrict__ exf,
    unsigned short* __restrict__ xT, unsigned short* __restrict__ vT)
{
    __shared__ float wq[64*68], wk[64*68], wv[64*68];
    const int t = threadIdx.x;
    for (int i = t; i < 4096; i += 256) {
        const int d = i >> 6, e = i & 63;
        wq[d*68+e] = Wq[i]; wk[d*68+e] = Wk[i]; wv[d*68+e] = Wv[i];
    }
    __syncthreads();
    const int row  = blockIdx.x * 32 + (t >> 3);
    const int b    = row >> 10, srow = row & 1023;
    const int dl   = t & 7;
    float xr[64];
    const float* xp = x + (size_t)row * 64;
    #pragma unroll
    for (int i = 0; i < 16; ++i) {
        f32x4 v = *(const f32x4*)(xp + i*4);
        xr[i*4+0]=v[0]; xr[i*4+1]=v[1]; xr[i*4+2]=v[2]; xr[i*4+3]=v[3];
    }
    const float C2 = 2.8853900817779268f;   // 2*log2(e)
    #pragma unroll
    for (int jd = 0; jd < 8; ++jd) {
        const int d = dl + jd*8;
        const float* pq = wq + d*68;
        const float* pk = wk + d*68;
        const float* pv = wv + d*68;
        float aq = 0.f, ak = 0.f, av = 0.f;
        #pragma unroll
        for (int e4 = 0; e4 < 16; ++e4) {
            f32x4 q4 = *(const f32x4*)(pq + e4*4);
            f32x4 k4 = *(const f32x4*)(pk + e4*4);
            f32x4 v4 = *(const f32x4*)(pv + e4*4);
            #pragma unroll
            for (int u = 0; u < 4; ++u) {
                aq += xr[e4*4+u]*q4[u];
                ak += xr[e4*4+u]*k4[u];
                av += xr[e4*4+u]*v4[u];
            }
        }
        ak += bkv[d];
        q32[(size_t)row*64 + d] = aq;
        k32[(size_t)row*64 + d] = ak;
        exf[(size_t)row*64 + d] = fast_exp2(C2 * xr[d]);
        xT[((size_t)b*64 + d)*1024 + srow] = f2bf(xr[d]);
        vT[((size_t)b*64 + d)*1024 + srow] = f2bf(av);
    }
}

// ---------------------------------------------------------------------------
// K2a: s1 = x.x^T, s2 = (q.k^T)*0.125*attn_scale over causal 32x64 tiles.
// grid 1088 = B * tri(16) * 2, block 256. LDS 52 KB -> 3 blocks/CU.
// ---------------------------------------------------------------------------
__global__ __launch_bounds__(256) void k_s12(
    const float* __restrict__ x, const float* __restrict__ q32,
    const float* __restrict__ k32, const float* __restrict__ attn_scale,
    float* __restrict__ sc)
{
    __shared__ float sxq[32*68], sq[32*68], sxk[64*68], sk[64*68];
    const int t = threadIdx.x;
    const int idx = blockIdx.x;
    const int b = idx / 272;
    const int rem = idx % 272;
    const int ti = rem >> 1, half = rem & 1;
    int qt = 0;
    while ((qt+1)*(qt+2)/2 <= ti) ++qt;
    const int kt = ti - qt*(qt+1)/2;
    const int q0 = qt*64 + half*32, k0 = kt*64;

    {   // stage q-side (32 rows x 64)
        const int row = t >> 3, seg = (t & 7) * 8;
        const float* gx = x   + ((size_t)b*SS + q0 + row)*64 + seg;
        const float* gq = q32 + ((size_t)b*SS + q0 + row)*64 + seg;
        f32x4* dx = (f32x4*)(sxq + row*68 + seg);
        f32x4* dq = (f32x4*)(sq  + row*68 + seg);
        dx[0] = *(const f32x4*)(gx);   dx[1] = *(const f32x4*)(gx+4);
        dq[0] = *(const f32x4*)(gq);   dq[1] = *(const f32x4*)(gq+4);
    }
    {   // stage k-side (64 rows x 64)
        const int row = t >> 2, seg = (t & 3) * 16;
        const float* gx = x   + ((size_t)b*SS + k0 + row)*64 + seg;
        const float* gk = k32 + ((size_t)b*SS + k0 + row)*64 + seg;
        f32x4* dx = (f32x4*)(sxk + row*68 + seg);
        f32x4* dk = (f32x4*)(sk  + row*68 + seg);
        #pragma unroll
        for (int i = 0; i < 4; ++i) {
            dx[i] = *(const f32x4*)(gx + i*4);
            dk[i] = *(const f32x4*)(gk + i*4);
        }
    }
    __syncthreads();

    const int qp = t >> 4;        // rows qp*2 + i
    const int kb = t & 15;        // cols kb + 16*j
    float a1[2][4] = {}, a2[2][4] = {};
    #pragma unroll 4
    for (int d0 = 0; d0 < 64; d0 += 4) {
        f32x4 xq[2], qq[2], xk[4], kk[4];
        #pragma unroll
        for (int i = 0; i < 2; ++i) {
            xq[i] = *(const f32x4*)(sxq + (qp*2+i)*68 + d0);
            qq[i] = *(const f32x4*)(sq  + (qp*2+i)*68 + d0);
        }
        #pragma unroll
        for (int j = 0; j < 4; ++j) {
            xk[j] = *(const f32x4*)(sxk + (kb + 16*j)*68 + d0);
            kk[j] = *(const f32x4*)(sk  + (kb + 16*j)*68 + d0);
        }
        #pragma unroll
        for (int i = 0; i < 2; ++i)
        #pragma unroll
        for (int j = 0; j < 4; ++j)
        #pragma unroll
        for (int dd = 0; dd < 4; ++dd) {
            a1[i][j] += xq[i][dd]*xk[j][dd];
            a2[i][j] += qq[i][dd]*kk[j][dd];
        }
    }
    const float s2s = 0.125f * attn_scale[0];
    const size_t plane = (size_t)SS*SS;
    float* p1 = sc + ((size_t)0*BB + b)*plane;
    float* p2 = sc + ((size_t)1*BB + b)*plane;
    #pragma unroll
    for (int i = 0; i < 2; ++i) {
        const int qrow = q0 + qp*2 + i;
        const size_t rb = (size_t)qrow*SS + k0 + kb;
        #pragma unroll
        for (int j = 0; j < 4; ++j) {
            p1[rb + 16*j] = a1[i][j];
            p2[rb + 16*j] = a2[i][j]*s2s;
        }
    }
}

// ---------------------------------------------------------------------------
// K2b: s3 = sum_d tanh(xq+xk) = 64 - 2*sum_d 1/(1 + exq[d]*exk[d]).
// 4-way rational combine: one v_rcp per 4 d's. LDS 26 KB -> 6 blocks/CU.
// grid 1088, block 256.
// ---------------------------------------------------------------------------
__global__ __launch_bounds__(256) void k_s3(
    const float* __restrict__ exf, float* __restrict__ sc)
{
    __shared__ float sexq[32*68], sexk[64*68];
    const int t = threadIdx.x;
    const int idx = blockIdx.x;
    const int b = idx / 272;
    const int rem = idx % 272;
    const int ti = rem >> 1, half = rem & 1;
    int qt = 0;
    while ((qt+1)*(qt+2)/2 <= ti) ++qt;
    const int kt = ti - qt*(qt+1)/2;
    const int q0 = qt*64 + half*32, k0 = kt*64;

    {   // stage q-side (32 rows x 64)
        const int row = t >> 3, seg = (t & 7) * 8;
        const float* g = exf + ((size_t)b*SS + q0 + row)*64 + seg;
        f32x4* dst = (f32x4*)(sexq + row*68 + seg);
        dst[0] = *(const f32x4*)(g); dst[1] = *(const f32x4*)(g+4);
    }
    {   // stage k-side (64 rows x 64)
        const int row = t >> 2, seg = (t & 3) * 16;
        const float* g = exf + ((size_t)b*SS + k0 + row)*64 + seg;
        f32x4* dst = (f32x4*)(sexk + row*68 + seg);
        #pragma unroll
        for (int i = 0; i < 4; ++i) dst[i] = *(const f32x4*)(g + i*4);
    }
    __syncthreads();

    const int qp = t >> 4;        // rows qp*2 + i
    const int kb = t & 15;        // cols kb + 16*j
    float ar[2][4] = {};
    #pragma unroll 4
    for (int d0 = 0; d0 < 64; d0 += 4) {
        f32x4 eq[2], ek[4];
        #pragma unroll
        for (int i = 0; i < 2; ++i)
            eq[i] = *(const f32x4*)(sexq + (qp*2+i)*68 + d0);
        #pragma unroll
        for (int j = 0; j < 4; ++j)
            ek[j] = *(const f32x4*)(sexk + (kb + 16*j)*68 + d0);
        #pragma unroll
        for (int i = 0; i < 2; ++i)
        #pragma unroll
        for (int j = 0; j < 4; ++j) {
            // sum of 4 sigmoids 1/(1+t) with one reciprocal
            float A = __builtin_fmaf(eq[i][0], ek[j][0], 1.0f);
            float Bv= __builtin_fmaf(eq[i][1], ek[j][1], 1.0f);
            float C = __builtin_fmaf(eq[i][2], ek[j][2], 1.0f);
            float Dv= __builtin_fmaf(eq[i][3], ek[j][3], 1.0f);
            float AB = A*Bv, CD = C*Dv;
            float num = __builtin_fmaf(A+Bv, CD, (C+Dv)*AB);
            float den = AB*CD;
            ar[i][j] = __builtin_fmaf(num, fast_rcp(den), ar[i][j]);
        }
    }
    const size_t plane = (size_t)SS*SS;
    float* p3 = sc + ((size_t)2*BB + b)*plane;
    #pragma unroll
    for (int i = 0; i < 2; ++i) {
        const int qrow = q0 + qp*2 + i;
        const size_t rb = (size_t)qrow*SS + k0 + kb;
        #pragma unroll
        for (int j = 0; j < 4; ++j)
            p3[rb + 16*j] = 64.0f - 2.0f*ar[i][j];
    }
}

// ---------------------------------------------------------------------------
// K3: one WAVE per (branch, b, 16-row q-tile). No LDS, no barriers.
// A-frag (P) is lane-local: lane computes P[row=lane&15][k=(lane>>4)*8+j]
// from sc + exp2; B-frag read straight from xT/vT (bf16 [B,D,S], L2-res).
// Writes weighted, normalized branch partials to po[3][B,S,D].
// grid 768 x 64.
// ---------------------------------------------------------------------------
__global__ __launch_bounds__(64) void k_out2(
    const float* __restrict__ sc, const unsigned short* __restrict__ xT,
    const unsigned short* __restrict__ vT, const float* __restrict__ attn_w,
    float* __restrict__ po)
{
    const int lane = threadIdx.x;
    const int bx = blockIdx.x;
    const int br = bx >> 8;            // 0..2
    const int b  = (bx >> 6) & 3;      // 0..3
    const int qt = bx & 63;            // 0..63
    const int q0 = qt*16, KE = q0 + 16;
    const int row = lane & 15, grp = lane >> 4;
    const int q = q0 + row;
    const float* sp = sc + ((size_t)br*BB + b)*((size_t)SS*SS) + (size_t)q*SS;
    const unsigned short* Vt = ((br == 1) ? vT : xT) + (size_t)b*64*1024;
    const float LOG2E = 1.4426950408889634f;

    // pass 1: causal row max (row = lane&15; 4 lane-groups split k)
    float m = -3.0e38f;
    for (int k = grp*4; k < KE; k += 16) {
        f32x4 s4 = *(const f32x4*)(sp + k);
        #pragma unroll
        for (int j = 0; j < 4; ++j)
            if (k + j <= q) m = fmaxf(m, s4[j]);
    }
    m = fmaxf(m, __shfl_xor(m, 16, 64));
    m = fmaxf(m, __shfl_xor(m, 32, 64));

    // pass 2: exp -> bf16 A-frag -> MFMA against 4 d-blocks of V^T
    float lsum = 0.f;
    f32x4 acc0 = {0,0,0,0}, acc1 = {0,0,0,0}, acc2 = {0,0,0,0}, acc3 = {0,0,0,0};
    for (int kc = 0; kc < KE; kc += 32) {
        const int kb8 = kc + grp*8;
        f32x4 s4a = *(const f32x4*)(sp + kb8);
        f32x4 s4b = *(const f32x4*)(sp + kb8 + 4);
        float e[8];
        #pragma unroll
        for (int j = 0; j < 4; ++j) {
            e[j]   = (kb8 + j     <= q) ? fast_exp2((s4a[j]-m)*LOG2E) : 0.f;
            e[j+4] = (kb8 + 4 + j <= q) ? fast_exp2((s4b[j]-m)*LOG2E) : 0.f;
        }
        #pragma unroll
        for (int j = 0; j < 8; ++j) lsum += e[j];
        bf16x8 af;
        #pragma unroll
        for (int j = 0; j < 8; ++j) af[j] = (short)f2bf(e[j]);
        {
            bf16x8 bf0 = *(const bf16x8*)(Vt + (size_t)( 0 + row)*1024 + kb8);
            bf16x8 bf1 = *(const bf16x8*)(Vt + (size_t)(16 + row)*1024 + kb8);
            bf16x8 bf2 = *(const bf16x8*)(Vt + (size_t)(32 + row)*1024 + kb8);
            bf16x8 bf3 = *(const bf16x8*)(Vt + (size_t)(48 + row)*1024 + kb8);
            acc0 = __builtin_amdgcn_mfma_f32_16x16x32_bf16(af, bf0, acc0, 0, 0, 0);
            acc1 = __builtin_amdgcn_mfma_f32_16x16x32_bf16(af, bf1, acc1, 0, 0, 0);
            acc2 = __builtin_amdgcn_mfma_f32_16x16x32_bf16(af, bf2, acc2, 0, 0, 0);
            acc3 = __builtin_amdgcn_mfma_f32_16x16x32_bf16(af, bf3, acc3, 0, 0, 0);
        }
    }
    lsum += __shfl_xor(lsum, 16, 64);
    lsum += __shfl_xor(lsum, 32, 64);

    const float aw0 = attn_w[0], aw1 = attn_w[1], aw2 = attn_w[2];
    const float wsum = aw0 + aw1 + aw2;
    const float wbr = ((br == 0) ? aw0 : (br == 1) ? aw1 : aw2) / wsum;

    // C layout: lane holds rows grp*4+i, col = row(=lane&15); row-sums live
    // on lane r for row r -> shfl.
    float* pob = po + ((size_t)br*BB + b)*((size_t)SS*64);
    #pragma unroll
    for (int i = 0; i < 4; ++i) {
        const int r = grp*4 + i;
        const float scale = wbr * fast_rcp(__shfl(lsum, r, 64));
        float* dst = pob + (size_t)(q0 + r)*64 + row;
        dst[ 0] = acc0[i]*scale;
        dst[16] = acc1[i]*scale;
        dst[32] = acc2[i]*scale;
        dst[48] = acc3[i]*scale;
    }
}

// ---------------------------------------------------------------------------
// K4: out = po[0] + po[1] + po[2]   (f32x4, 256 blocks x 256)
// ---------------------------------------------------------------------------
__global__ __launch_bounds__(256) void k_comb(
    const float* __restrict__ po, float* __restrict__ out)
{
    const int i = blockIdx.x*256 + threadIdx.x;       // 65536 f32x4's
    const f32x4* p = (const f32x4*)po;
    f32x4 a = p[i];
    f32x4 bq = p[i + 65536];
    f32x4 c = p[i + 131072];
    ((f32x4*)out)[i] = a + bq + c;
}

extern "C" void kernel_launch(void* const* d_in, const int* in_sizes, int n_in,
                              void* d_out, int out_size, void* d_ws, size_t ws_size,
                              hipStream_t stream) {
    (void)in_sizes; (void)n_in; (void)out_size; (void)ws_size;
    const float* x          = (const float*)d_in[0];
    const float* Wq         = (const float*)d_in[1];
    const float* Wk         = (const float*)d_in[2];
    const float* bk         = (const float*)d_in[3];
    const float* Wv         = (const float*)d_in[4];
    const float* attn_w     = (const float*)d_in[5];
    const float* attn_scale = (const float*)d_in[6];
    float* out              = (float*)d_out;

    // workspace carve-up (~55.3 MB)
    float* sc  = (float*)d_ws;                          // [3][B][S][S] f32
    float* q32 = sc + (size_t)3*BB*SS*SS;
    float* k32 = q32 + (size_t)BB*SS*DDIM;
    float* exf = k32 + (size_t)BB*SS*DDIM;
    unsigned short* xT = (unsigned short*)(exf + (size_t)BB*SS*DDIM); // [B][D][S] bf16
    unsigned short* vT = xT + (size_t)BB*DDIM*SS;
    float* po  = (float*)(vT + (size_t)BB*DDIM*SS);     // [3][B][S][D] f32

    k_proj<<<128, 256, 0, stream>>>(x, Wq, Wk, bk, Wv, q32, k32, exf, xT, vT);
    k_s12 <<<1088, 256, 0, stream>>>(x, q32, k32, attn_scale, sc);
    k_s3  <<<1088, 256, 0, stream>>>(exf, sc);
    k_out2<<<768, 64, 0, stream>>>(sc, xT, vT, attn_w, po);
    k_comb<<<256, 256, 0, stream>>>(po, out);
}

// Round 4
// 85.484 us; speedup vs baseline: 1.1733x; 1.0087x over previous
//
#include <hip/hip_runtime.h>
#include <hip/hip_bf16.h>

#define BB 4
#define SS 1024
#define DDIM 64

typedef __attribute__((ext_vector_type(4))) float f32x4;
typedef __attribute__((ext_vector_type(8))) short bf16x8;

__device__ __forceinline__ float fast_exp2(float x) { return __builtin_amdgcn_exp2f(x); }
__device__ __forceinline__ float fast_rcp(float x)  { return __builtin_amdgcn_rcpf(x); }

// float -> bf16 bits, round-to-nearest-even (finite inputs only)
__device__ __forceinline__ unsigned short f2bf(float f) {
    unsigned int u = __builtin_bit_cast(unsigned int, f);
    u += 0x7fffu + ((u >> 16) & 1u);
    return (unsigned short)(u >> 16);
}

// ---------------------------------------------------------------------------
// K1 v2: projections, no per-thread arrays (v1 spilled xr[64] to scratch ->
// 52us latency-bound). 1024 blocks x 256 thr, 4 rows/block.
// Thread: row r = t&3, col cc = t>>2. x rows in LDS (broadcast reads);
// W rows streamed from global (L1-resident, same 48KB per block).
// q=x@Wq^T, k=x@Wk^T+bk, v=x@Wv^T; exf=exp2(2log2e*x); xT,vT bf16 [B,D,S].
// ---------------------------------------------------------------------------
__global__ __launch_bounds__(256) void k_proj(
    const float* __restrict__ x, const float* __restrict__ Wq,
    const float* __restrict__ Wk, const float* __restrict__ bkv,
    const float* __restrict__ Wv,
    float* __restrict__ q32, float* __restrict__ k32, float* __restrict__ exf,
    unsigned short* __restrict__ xT, unsigned short* __restrict__ vT)
{
    __shared__ float xl[4*68];
    const int t = threadIdx.x;
    const int r = t & 3, cc = t >> 2;
    const int row0 = blockIdx.x * 4;
    if (t < 64) {
        const int rr = t >> 4, seg = (t & 15) * 4;
        *(f32x4*)(xl + rr*68 + seg) =
            *(const f32x4*)(x + (size_t)(row0 + rr)*64 + seg);
    }
    __syncthreads();

    const float* wqp = Wq + cc*64;
    const float* wkp = Wk + cc*64;
    const float* wvp = Wv + cc*64;
    float aq = 0.f, ak = 0.f, av = 0.f;
    #pragma unroll 4
    for (int e0 = 0; e0 < 64; e0 += 4) {
        f32x4 xv = *(const f32x4*)(xl + r*68 + e0);
        f32x4 q4 = *(const f32x4*)(wqp + e0);
        f32x4 k4 = *(const f32x4*)(wkp + e0);
        f32x4 v4 = *(const f32x4*)(wvp + e0);
        #pragma unroll
        for (int u = 0; u < 4; ++u) {
            aq = __builtin_fmaf(xv[u], q4[u], aq);
            ak = __builtin_fmaf(xv[u], k4[u], ak);
            av = __builtin_fmaf(xv[u], v4[u], av);
        }
    }
    const int row = row0 + r;
    const int b = row >> 10, srow = row & 1023;
    const float C2 = 2.8853900817779268f;   // 2*log2(e)
    ak += bkv[cc];
    const float xs = xl[r*68 + cc];
    q32[(size_t)row*64 + cc] = aq;
    k32[(size_t)row*64 + cc] = ak;
    exf[(size_t)row*64 + cc] = fast_exp2(C2 * xs);
    xT[((size_t)b*64 + cc)*1024 + srow] = f2bf(xs);
    vT[((size_t)b*64 + cc)*1024 + srow] = f2bf(av);
}

// ---------------------------------------------------------------------------
// K2a: s1 = x.x^T, s2 = (q.k^T)*0.125*attn_scale over causal 32x64 tiles.
// grid 1088 = B * tri(16) * 2, block 256. LDS 52 KB -> 3 blocks/CU.
// ---------------------------------------------------------------------------
__global__ __launch_bounds__(256) void k_s12(
    const float* __restrict__ x, const float* __restrict__ q32,
    const float* __restrict__ k32, const float* __restrict__ attn_scale,
    float* __restrict__ sc)
{
    __shared__ float sxq[32*68], sq[32*68], sxk[64*68], sk[64*68];
    const int t = threadIdx.x;
    const int idx = blockIdx.x;
    const int b = idx / 272;
    const int rem = idx % 272;
    const int ti = rem >> 1, half = rem & 1;
    int qt = 0;
    while ((qt+1)*(qt+2)/2 <= ti) ++qt;
    const int kt = ti - qt*(qt+1)/2;
    const int q0 = qt*64 + half*32, k0 = kt*64;

    {   // stage q-side (32 rows x 64)
        const int row = t >> 3, seg = (t & 7) * 8;
        const float* gx = x   + ((size_t)b*SS + q0 + row)*64 + seg;
        const float* gq = q32 + ((size_t)b*SS + q0 + row)*64 + seg;
        f32x4* dx = (f32x4*)(sxq + row*68 + seg);
        f32x4* dq = (f32x4*)(sq  + row*68 + seg);
        dx[0] = *(const f32x4*)(gx);   dx[1] = *(const f32x4*)(gx+4);
        dq[0] = *(const f32x4*)(gq);   dq[1] = *(const f32x4*)(gq+4);
    }
    {   // stage k-side (64 rows x 64)
        const int row = t >> 2, seg = (t & 3) * 16;
        const float* gx = x   + ((size_t)b*SS + k0 + row)*64 + seg;
        const float* gk = k32 + ((size_t)b*SS + k0 + row)*64 + seg;
        f32x4* dx = (f32x4*)(sxk + row*68 + seg);
        f32x4* dk = (f32x4*)(sk  + row*68 + seg);
        #pragma unroll
        for (int i = 0; i < 4; ++i) {
            dx[i] = *(const f32x4*)(gx + i*4);
            dk[i] = *(const f32x4*)(gk + i*4);
        }
    }
    __syncthreads();

    const int qp = t >> 4;        // rows qp*2 + i
    const int kb = t & 15;        // cols kb + 16*j
    float a1[2][4] = {}, a2[2][4] = {};
    #pragma unroll 4
    for (int d0 = 0; d0 < 64; d0 += 4) {
        f32x4 xq[2], qq[2], xk[4], kk[4];
        #pragma unroll
        for (int i = 0; i < 2; ++i) {
            xq[i] = *(const f32x4*)(sxq + (qp*2+i)*68 + d0);
            qq[i] = *(const f32x4*)(sq  + (qp*2+i)*68 + d0);
        }
        #pragma unroll
        for (int j = 0; j < 4; ++j) {
            xk[j] = *(const f32x4*)(sxk + (kb + 16*j)*68 + d0);
            kk[j] = *(const f32x4*)(sk  + (kb + 16*j)*68 + d0);
        }
        #pragma unroll
        for (int i = 0; i < 2; ++i)
        #pragma unroll
        for (int j = 0; j < 4; ++j)
        #pragma unroll
        for (int dd = 0; dd < 4; ++dd) {
            a1[i][j] += xq[i][dd]*xk[j][dd];
            a2[i][j] += qq[i][dd]*kk[j][dd];
        }
    }
    const float s2s = 0.125f * attn_scale[0];
    const size_t plane = (size_t)SS*SS;
    float* p1 = sc + ((size_t)0*BB + b)*plane;
    float* p2 = sc + ((size_t)1*BB + b)*plane;
    #pragma unroll
    for (int i = 0; i < 2; ++i) {
        const int qrow = q0 + qp*2 + i;
        const size_t rb = (size_t)qrow*SS + k0 + kb;
        #pragma unroll
        for (int j = 0; j < 4; ++j) {
            p1[rb + 16*j] = a1[i][j];
            p2[rb + 16*j] = a2[i][j]*s2s;
        }
    }
}

// ---------------------------------------------------------------------------
// K2b: s3 = sum_d tanh(xq+xk) = 64 - 2*sum_d 1/(1 + exq[d]*exk[d]).
// 4-way rational combine: one v_rcp per 4 d's. LDS 26 KB -> 6 blocks/CU.
// grid 1088, block 256.
// ---------------------------------------------------------------------------
__global__ __launch_bounds__(256) void k_s3(
    const float* __restrict__ exf, float* __restrict__ sc)
{
    __shared__ float sexq[32*68], sexk[64*68];
    const int t = threadIdx.x;
    const int idx = blockIdx.x;
    const int b = idx / 272;
    const int rem = idx % 272;
    const int ti = rem >> 1, half = rem & 1;
    int qt = 0;
    while ((qt+1)*(qt+2)/2 <= ti) ++qt;
    const int kt = ti - qt*(qt+1)/2;
    const int q0 = qt*64 + half*32, k0 = kt*64;

    {   // stage q-side (32 rows x 64)
        const int row = t >> 3, seg = (t & 7) * 8;
        const float* g = exf + ((size_t)b*SS + q0 + row)*64 + seg;
        f32x4* dst = (f32x4*)(sexq + row*68 + seg);
        dst[0] = *(const f32x4*)(g); dst[1] = *(const f32x4*)(g+4);
    }
    {   // stage k-side (64 rows x 64)
        const int row = t >> 2, seg = (t & 3) * 16;
        const float* g = exf + ((size_t)b*SS + k0 + row)*64 + seg;
        f32x4* dst = (f32x4*)(sexk + row*68 + seg);
        #pragma unroll
        for (int i = 0; i < 4; ++i) dst[i] = *(const f32x4*)(g + i*4);
    }
    __syncthreads();

    const int qp = t >> 4;        // rows qp*2 + i
    const int kb = t & 15;        // cols kb + 16*j
    float ar[2][4] = {};
    #pragma unroll 4
    for (int d0 = 0; d0 < 64; d0 += 4) {
        f32x4 eq[2], ek[4];
        #pragma unroll
        for (int i = 0; i < 2; ++i)
            eq[i] = *(const f32x4*)(sexq + (qp*2+i)*68 + d0);
        #pragma unroll
        for (int j = 0; j < 4; ++j)
            ek[j] = *(const f32x4*)(sexk + (kb + 16*j)*68 + d0);
        #pragma unroll
        for (int i = 0; i < 2; ++i)
        #pragma unroll
        for (int j = 0; j < 4; ++j) {
            // sum of 4 sigmoids 1/(1+t) with one reciprocal
            float A = __builtin_fmaf(eq[i][0], ek[j][0], 1.0f);
            float Bv= __builtin_fmaf(eq[i][1], ek[j][1], 1.0f);
            float C = __builtin_fmaf(eq[i][2], ek[j][2], 1.0f);
            float Dv= __builtin_fmaf(eq[i][3], ek[j][3], 1.0f);
            float AB = A*Bv, CD = C*Dv;
            float num = __builtin_fmaf(A+Bv, CD, (C+Dv)*AB);
            float den = AB*CD;
            ar[i][j] = __builtin_fmaf(num, fast_rcp(den), ar[i][j]);
        }
    }
    const size_t plane = (size_t)SS*SS;
    float* p3 = sc + ((size_t)2*BB + b)*plane;
    #pragma unroll
    for (int i = 0; i < 2; ++i) {
        const int qrow = q0 + qp*2 + i;
        const size_t rb = (size_t)qrow*SS + k0 + kb;
        #pragma unroll
        for (int j = 0; j < 4; ++j)
            p3[rb + 16*j] = 64.0f - 2.0f*ar[i][j];
    }
}

// ---------------------------------------------------------------------------
// K3: one WAVE per (branch, b, 16-row q-tile). No LDS, no barriers.
// A-frag (P) is lane-local; B-frag read straight from xT/vT (bf16 [B,D,S]).
// Writes weighted, normalized branch partials to po[3][B,S,D]. grid 768x64.
// ---------------------------------------------------------------------------
__global__ __launch_bounds__(64) void k_out2(
    const float* __restrict__ sc, const unsigned short* __restrict__ xT,
    const unsigned short* __restrict__ vT, const float* __restrict__ attn_w,
    float* __restrict__ po)
{
    const int lane = threadIdx.x;
    const int bx = blockIdx.x;
    const int br = bx >> 8;            // 0..2
    const int b  = (bx >> 6) & 3;      // 0..3
    const int qt = bx & 63;            // 0..63
    const int q0 = qt*16, KE = q0 + 16;
    const int row = lane & 15, grp = lane >> 4;
    const int q = q0 + row;
    const float* sp = sc + ((size_t)br*BB + b)*((size_t)SS*SS) + (size_t)q*SS;
    const unsigned short* Vt = ((br == 1) ? vT : xT) + (size_t)b*64*1024;
    const float LOG2E = 1.4426950408889634f;

    // pass 1: causal row max (row = lane&15; 4 lane-groups split k)
    float m = -3.0e38f;
    for (int k = grp*4; k < KE; k += 16) {
        f32x4 s4 = *(const f32x4*)(sp + k);
        #pragma unroll
        for (int j = 0; j < 4; ++j)
            if (k + j <= q) m = fmaxf(m, s4[j]);
    }
    m = fmaxf(m, __shfl_xor(m, 16, 64));
    m = fmaxf(m, __shfl_xor(m, 32, 64));

    // pass 2: exp -> bf16 A-frag -> MFMA against 4 d-blocks of V^T
    float lsum = 0.f;
    f32x4 acc0 = {0,0,0,0}, acc1 = {0,0,0,0}, acc2 = {0,0,0,0}, acc3 = {0,0,0,0};
    for (int kc = 0; kc < KE; kc += 32) {
        const int kb8 = kc + grp*8;
        f32x4 s4a = *(const f32x4*)(sp + kb8);
        f32x4 s4b = *(const f32x4*)(sp + kb8 + 4);
        float e[8];
        #pragma unroll
        for (int j = 0; j < 4; ++j) {
            e[j]   = (kb8 + j     <= q) ? fast_exp2((s4a[j]-m)*LOG2E) : 0.f;
            e[j+4] = (kb8 + 4 + j <= q) ? fast_exp2((s4b[j]-m)*LOG2E) : 0.f;
        }
        #pragma unroll
        for (int j = 0; j < 8; ++j) lsum += e[j];
        bf16x8 af;
        #pragma unroll
        for (int j = 0; j < 8; ++j) af[j] = (short)f2bf(e[j]);
        {
            bf16x8 bf0 = *(const bf16x8*)(Vt + (size_t)( 0 + row)*1024 + kb8);
            bf16x8 bf1 = *(const bf16x8*)(Vt + (size_t)(16 + row)*1024 + kb8);
            bf16x8 bf2 = *(const bf16x8*)(Vt + (size_t)(32 + row)*1024 + kb8);
            bf16x8 bf3 = *(const bf16x8*)(Vt + (size_t)(48 + row)*1024 + kb8);
            acc0 = __builtin_amdgcn_mfma_f32_16x16x32_bf16(af, bf0, acc0, 0, 0, 0);
            acc1 = __builtin_amdgcn_mfma_f32_16x16x32_bf16(af, bf1, acc1, 0, 0, 0);
            acc2 = __builtin_amdgcn_mfma_f32_16x16x32_bf16(af, bf2, acc2, 0, 0, 0);
            acc3 = __builtin_amdgcn_mfma_f32_16x16x32_bf16(af, bf3, acc3, 0, 0, 0);
        }
    }
    lsum += __shfl_xor(lsum, 16, 64);
    lsum += __shfl_xor(lsum, 32, 64);

    const float aw0 = attn_w[0], aw1 = attn_w[1], aw2 = attn_w[2];
    const float wsum = aw0 + aw1 + aw2;
    const float wbr = ((br == 0) ? aw0 : (br == 1) ? aw1 : aw2) / wsum;

    float* pob = po + ((size_t)br*BB + b)*((size_t)SS*64);
    #pragma unroll
    for (int i = 0; i < 4; ++i) {
        const int r = grp*4 + i;
        const float scale = wbr * fast_rcp(__shfl(lsum, r, 64));
        float* dst = pob + (size_t)(q0 + r)*64 + row;
        dst[ 0] = acc0[i]*scale;
        dst[16] = acc1[i]*scale;
        dst[32] = acc2[i]*scale;
        dst[48] = acc3[i]*scale;
    }
}

// ---------------------------------------------------------------------------
// K4: out = po[0] + po[1] + po[2]   (f32x4, 256 blocks x 256)
// ---------------------------------------------------------------------------
__global__ __launch_bounds__(256) void k_comb(
    const float* __restrict__ po, float* __restrict__ out)
{
    const int i = blockIdx.x*256 + threadIdx.x;       // 65536 f32x4's
    const f32x4* p = (const f32x4*)po;
    f32x4 a = p[i];
    f32x4 bq = p[i + 65536];
    f32x4 c = p[i + 131072];
    ((f32x4*)out)[i] = a + bq + c;
}

extern "C" void kernel_launch(void* const* d_in, const int* in_sizes, int n_in,
                              void* d_out, int out_size, void* d_ws, size_t ws_size,
                              hipStream_t stream) {
    (void)in_sizes; (void)n_in; (void)out_size; (void)ws_size;
    const float* x          = (const float*)d_in[0];
    const float* Wq         = (const float*)d_in[1];
    const float* Wk         = (const float*)d_in[2];
    const float* bk         = (const float*)d_in[3];
    const float* Wv         = (const float*)d_in[4];
    const float* attn_w     = (const float*)d_in[5];
    const float* attn_scale = (const float*)d_in[6];
    float* out              = (float*)d_out;

    // workspace carve-up (~55.3 MB)
    float* sc  = (float*)d_ws;                          // [3][B][S][S] f32
    float* q32 = sc + (size_t)3*BB*SS*SS;
    float* k32 = q32 + (size_t)BB*SS*DDIM;
    float* exf = k32 + (size_t)BB*SS*DDIM;
    unsigned short* xT = (unsigned short*)(exf + (size_t)BB*SS*DDIM); // [B][D][S] bf16
    unsigned short* vT = xT + (size_t)BB*DDIM*SS;
    float* po  = (float*)(vT + (size_t)BB*DDIM*SS);     // [3][B][S][D] f32

    k_proj<<<1024, 256, 0, stream>>>(x, Wq, Wk, bk, Wv, q32, k32, exf, xT, vT);
    k_s12 <<<1088, 256, 0, stream>>>(x, q32, k32, attn_scale, sc);
    k_s3  <<<1088, 256, 0, stream>>>(exf, sc);
    k_out2<<<768, 64, 0, stream>>>(sc, xT, vT, attn_w, po);
    k_comb<<<256, 256, 0, stream>>>(po, out);
}

// Round 5
// 71.927 us; speedup vs baseline: 1.3945x; 1.1885x over previous
//
#include <hip/hip_runtime.h>
#include <hip/hip_bf16.h>

#define BB 4
#define SS 1024
#define DDIM 64
#define NSD (BB*SS*DDIM)

typedef __attribute__((ext_vector_type(4))) float f32x4;
typedef __attribute__((ext_vector_type(8))) short bf16x8;

__device__ __forceinline__ float fast_exp2(float x) { return __builtin_amdgcn_exp2f(x); }
__device__ __forceinline__ float fast_rcp(float x)  { return __builtin_amdgcn_rcpf(x); }

// float -> bf16 bits, round-to-nearest-even (finite inputs only)
__device__ __forceinline__ unsigned short f2bf(float f) {
    unsigned int u = __builtin_bit_cast(unsigned int, f);
    u += 0x7fffu + ((u >> 16) & 1u);
    return (unsigned short)(u >> 16);
}

// ---------------------------------------------------------------------------
// K1: projections (round-4 version, no per-thread arrays). 1024 blocks x 256.
// Thread: row r = t&3 (4 rows/block), col cc = t>>2. x rows in LDS broadcast;
// W rows streamed from global (L1-resident).
// q=x@Wq^T, k=x@Wk^T+bk, v=x@Wv^T; exf=exp2(2log2e*x); xT,vT bf16 [B,D,S].
// ---------------------------------------------------------------------------
__global__ __launch_bounds__(256) void k_proj(
    const float* __restrict__ x, const float* __restrict__ Wq,
    const float* __restrict__ Wk, const float* __restrict__ bkv,
    const float* __restrict__ Wv,
    float* __restrict__ q32, float* __restrict__ k32, float* __restrict__ exf,
    unsigned short* __restrict__ xT, unsigned short* __restrict__ vT)
{
    __shared__ float xl[4*68];
    const int t = threadIdx.x;
    const int r = t & 3, cc = t >> 2;
    const int row0 = blockIdx.x * 4;
    if (t < 64) {
        const int rr = t >> 4, seg = (t & 15) * 4;
        *(f32x4*)(xl + rr*68 + seg) =
            *(const f32x4*)(x + (size_t)(row0 + rr)*64 + seg);
    }
    __syncthreads();

    const float* wqp = Wq + cc*64;
    const float* wkp = Wk + cc*64;
    const float* wvp = Wv + cc*64;
    float aq = 0.f, ak = 0.f, av = 0.f;
    #pragma unroll 4
    for (int e0 = 0; e0 < 64; e0 += 4) {
        f32x4 xv = *(const f32x4*)(xl + r*68 + e0);
        f32x4 q4 = *(const f32x4*)(wqp + e0);
        f32x4 k4 = *(const f32x4*)(wkp + e0);
        f32x4 v4 = *(const f32x4*)(wvp + e0);
        #pragma unroll
        for (int u = 0; u < 4; ++u) {
            aq = __builtin_fmaf(xv[u], q4[u], aq);
            ak = __builtin_fmaf(xv[u], k4[u], ak);
            av = __builtin_fmaf(xv[u], v4[u], av);
        }
    }
    const int row = row0 + r;
    const int b = row >> 10, srow = row & 1023;
    const float C2 = 2.8853900817779268f;   // 2*log2(e)
    ak += bkv[cc];
    const float xs = xl[r*68 + cc];
    q32[(size_t)row*64 + cc] = aq;
    k32[(size_t)row*64 + cc] = ak;
    exf[(size_t)row*64 + cc] = fast_exp2(C2 * xs);
    xT[((size_t)b*64 + cc)*1024 + srow] = f2bf(xs);
    vT[((size_t)b*64 + cc)*1024 + srow] = f2bf(av);
}

// ---------------------------------------------------------------------------
// K2: FUSED score+softmax+PV, one block per (split, br, b, 16-row q-tile).
// grid 1536 = 2*3*4*64, block 256 (4 waves). No sc tensor.
// Fixed per-branch exp shift (no max pass; shift-invariant in acc/l ratio):
//   br0: e^(s1-64); br1: e^(s2); br2: e^(s3), s3 in [-64,64].
// Scores f32 (k_s12/k_s3 verified inner loops); P bf16 -> LDS -> MFMA with
// V^T chunk staged from xT/vT (round-2-verified [*][72] layout).
// K-chunks split 2-way per q-tile (tail-kill); writes unnorm (acc,l) to po/lb.
// ---------------------------------------------------------------------------
__global__ __launch_bounds__(256) void k_fused(
    const float* __restrict__ x, const float* __restrict__ q32,
    const float* __restrict__ k32, const float* __restrict__ exf,
    const unsigned short* __restrict__ xT, const unsigned short* __restrict__ vT,
    const float* __restrict__ attn_scale,
    float* __restrict__ po, float* __restrict__ lb)
{
    __shared__ float sqd[16*68];
    __shared__ float skd[64*68];
    __shared__ unsigned short Vl[64*72];
    __shared__ unsigned short Pl[16*72];
    __shared__ float l_arr[16];

    const int t = threadIdx.x;
    const int bx = blockIdx.x;
    const int split = bx & 1;
    const int rem = bx >> 1;
    const int qt = 63 - (rem & 63);         // reversed: big tiles dispatch first
    const int brb = rem >> 6;               // 0..11
    const int br = brb >> 2, b = brb & 3;
    const int q0 = qt * 16;

    const float* qsrc = (br == 0) ? x : (br == 1) ? q32 : exf;
    const float* ksrc = (br == 0) ? x : (br == 1) ? k32 : exf;
    const unsigned short* Vt = ((br == 1) ? vT : xT) + (size_t)b*64*1024;
    const float s2s = 0.125f * attn_scale[0];
    const float LOG2E = 1.4426950408889634f;

    {   // stage q-side rows [16][68]
        const int qr = t >> 4, seg = (t & 15) * 4;
        *(f32x4*)(sqd + qr*68 + seg) =
            *(const f32x4*)(qsrc + ((size_t)b*SS + q0 + qr)*64 + seg);
    }

    const int nc = qt/4 + 1;                // k-chunks needed for this q-tile
    const int ncl = (nc + 1) >> 1;
    const int c0 = split ? ncl : 0;
    const int c1 = split ? nc : ncl;

    const int row = t >> 4, kb = t & 15;
    const int q = q0 + row;
    const int wv = t >> 6, lane = t & 63;
    float lsum = 0.f;
    f32x4 acc = {0.f,0.f,0.f,0.f};

    for (int c = c0; c < c1; ++c) {
        const int kc = c * 64;
        {   // stage k-side f32 [64][68]
            const int kr = t >> 2, seg = (t & 3) * 16;
            const float* g = ksrc + ((size_t)b*SS + kc + kr)*64 + seg;
            f32x4* d4 = (f32x4*)(skd + kr*68 + seg);
            #pragma unroll
            for (int i = 0; i < 4; ++i) d4[i] = *(const f32x4*)(g + i*4);
        }
        {   // stage V^T bf16 [64][72] (coalesced rows of xT/vT)
            const int dr = t >> 2, seg = (t & 3) * 16;   // shorts
            const unsigned short* g = Vt + (size_t)dr*1024 + kc + seg;
            *(f32x4*)(Vl + dr*72 + seg)     = *(const f32x4*)(g);
            *(f32x4*)(Vl + dr*72 + seg + 8) = *(const f32x4*)(g + 8);
        }
        __syncthreads();

        // scores: 1 row x 4 cols (kb + 16j) per thread, f32
        float s[4];
        if (br == 2) {
            float ar[4] = {0.f,0.f,0.f,0.f};
            #pragma unroll 4
            for (int d0 = 0; d0 < 64; d0 += 4) {
                f32x4 eq = *(const f32x4*)(sqd + row*68 + d0);
                f32x4 ek[4];
                #pragma unroll
                for (int j = 0; j < 4; ++j)
                    ek[j] = *(const f32x4*)(skd + (kb + 16*j)*68 + d0);
                #pragma unroll
                for (int j = 0; j < 4; ++j) {
                    float A = __builtin_fmaf(eq[0], ek[j][0], 1.0f);
                    float Bv= __builtin_fmaf(eq[1], ek[j][1], 1.0f);
                    float C = __builtin_fmaf(eq[2], ek[j][2], 1.0f);
                    float Dv= __builtin_fmaf(eq[3], ek[j][3], 1.0f);
                    float AB = A*Bv, CD = C*Dv;
                    float num = __builtin_fmaf(A+Bv, CD, (C+Dv)*AB);
                    ar[j] = __builtin_fmaf(num, fast_rcp(AB*CD), ar[j]);
                }
            }
            #pragma unroll
            for (int j = 0; j < 4; ++j) s[j] = 64.0f - 2.0f*ar[j];
        } else {
            float a[4] = {0.f,0.f,0.f,0.f};
            #pragma unroll 4
            for (int d0 = 0; d0 < 64; d0 += 4) {
                f32x4 eq = *(const f32x4*)(sqd + row*68 + d0);
                f32x4 ek[4];
                #pragma unroll
                for (int j = 0; j < 4; ++j)
                    ek[j] = *(const f32x4*)(skd + (kb + 16*j)*68 + d0);
                #pragma unroll
                for (int j = 0; j < 4; ++j)
                #pragma unroll
                for (int u = 0; u < 4; ++u)
                    a[j] = __builtin_fmaf(eq[u], ek[j][u], a[j]);
            }
            if (br == 0) {
                #pragma unroll
                for (int j = 0; j < 4; ++j) s[j] = a[j] - 64.0f;
            } else {
                #pragma unroll
                for (int j = 0; j < 4; ++j) s[j] = a[j] * s2s;
            }
        }
        // exp (fixed shift), causal mask, bf16 P to LDS
        #pragma unroll
        for (int j = 0; j < 4; ++j) {
            const int kg = kc + kb + 16*j;
            float e = (kg <= q) ? fast_exp2(s[j]*LOG2E) : 0.f;
            lsum += e;
            Pl[row*72 + kb + 16*j] = f2bf(e);
        }
        __syncthreads();
        // PV MFMA: wave wv owns d-block wv*16 (round-2-verified layout)
        #pragma unroll
        for (int ks = 0; ks < 2; ++ks) {
            bf16x8 af = *(const bf16x8*)(Pl + (lane & 15)*72 + ks*32 + (lane >> 4)*8);
            bf16x8 bf = *(const bf16x8*)(Vl + (wv*16 + (lane & 15))*72 + ks*32 + (lane >> 4)*8);
            acc = __builtin_amdgcn_mfma_f32_16x16x32_bf16(af, bf, acc, 0, 0, 0);
        }
        __syncthreads();
    }

    // row-sum reduce within each 16-thread row group (wave-local)
    lsum += __shfl_xor(lsum, 1, 64);
    lsum += __shfl_xor(lsum, 2, 64);
    lsum += __shfl_xor(lsum, 4, 64);
    lsum += __shfl_xor(lsum, 8, 64);
    if (kb == 0) l_arr[row] = lsum;
    __syncthreads();

    const size_t poi = (size_t)(split*3 + br)*4 + b;
    float* pob = po + poi*((size_t)SS*64) + (size_t)q0*64;
    #pragma unroll
    for (int i = 0; i < 4; ++i) {
        const int rr = (lane >> 4)*4 + i;
        pob[(size_t)rr*64 + wv*16 + (lane & 15)] = acc[i];
    }
    if (t < 16) lb[poi*SS + q0 + t] = l_arr[t];
}

// ---------------------------------------------------------------------------
// K3: merge splits + branches: out = sum_br wbr*(acc0+acc1)/(l0+l1).
// 256 blocks x 256, one f32x4 per thread.
// ---------------------------------------------------------------------------
__global__ __launch_bounds__(256) void k_comb(
    const float* __restrict__ po, const float* __restrict__ lb,
    const float* __restrict__ attn_w, float* __restrict__ out)
{
    const int v = blockIdx.x*256 + threadIdx.x;      // f32x4 index over [B,S,D]
    const int qg = v >> 4;                           // global row b*S+q
    const float aw0 = attn_w[0], aw1 = attn_w[1], aw2 = attn_w[2];
    const float iws = fast_rcp(aw0 + aw1 + aw2);
    const f32x4* p = (const f32x4*)po;
    f32x4 o = {0.f,0.f,0.f,0.f};
    #pragma unroll
    for (int br = 0; br < 3; ++br) {
        f32x4 a0 = p[(size_t)(0*3 + br)*65536 + v];
        f32x4 a1 = p[(size_t)(1*3 + br)*65536 + v];
        const float l = lb[(0*3 + br)*4096 + qg] + lb[(1*3 + br)*4096 + qg];
        const float w = ((br == 0) ? aw0 : (br == 1) ? aw1 : aw2) * iws;
        const float sfac = w * fast_rcp(l);
        f32x4 sum = a0 + a1;
        #pragma unroll
        for (int u = 0; u < 4; ++u) o[u] = __builtin_fmaf(sum[u], sfac, o[u]);
    }
    ((f32x4*)out)[v] = o;
}

extern "C" void kernel_launch(void* const* d_in, const int* in_sizes, int n_in,
                              void* d_out, int out_size, void* d_ws, size_t ws_size,
                              hipStream_t stream) {
    (void)in_sizes; (void)n_in; (void)out_size; (void)ws_size;
    const float* x          = (const float*)d_in[0];
    const float* Wq         = (const float*)d_in[1];
    const float* Wk         = (const float*)d_in[2];
    const float* bk         = (const float*)d_in[3];
    const float* Wv         = (const float*)d_in[4];
    const float* attn_w     = (const float*)d_in[5];
    const float* attn_scale = (const float*)d_in[6];
    float* out              = (float*)d_out;

    // workspace carve-up (~11 MB)
    float* q32 = (float*)d_ws;
    float* k32 = q32 + NSD;
    float* exf = k32 + NSD;
    unsigned short* xT = (unsigned short*)(exf + NSD);   // bf16 [B,D,S]
    unsigned short* vT = xT + NSD;
    float* po = (float*)(vT + NSD);                      // [2*3][B,S,D] f32
    float* lb = po + (size_t)6*BB*SS*DDIM;               // [2*3][B*S]

    k_proj <<<1024, 256, 0, stream>>>(x, Wq, Wk, bk, Wv, q32, k32, exf, xT, vT);
    k_fused<<<1536, 256, 0, stream>>>(x, q32, k32, exf, xT, vT, attn_scale, po, lb);
    k_comb <<<256, 256, 0, stream>>>(po, lb, attn_w, out);
}

// Round 6
// 50.573 us; speedup vs baseline: 1.9833x; 1.4222x over previous
//
#include <hip/hip_runtime.h>
#include <hip/hip_bf16.h>

#define BB 4
#define SS 1024
#define NSD (BB*SS*64)

typedef __attribute__((ext_vector_type(4))) float f32x4;
typedef __attribute__((ext_vector_type(8))) short bf16x8;

__device__ __forceinline__ float fast_exp2(float x) { return __builtin_amdgcn_exp2f(x); }
__device__ __forceinline__ float fast_rcp(float x)  { return __builtin_amdgcn_rcpf(x); }

__device__ __forceinline__ unsigned short f2bf(float f) {
    unsigned int u = __builtin_bit_cast(unsigned int, f);
    u += 0x7fffu + ((u >> 16) & 1u);
    return (unsigned short)(u >> 16);
}
__device__ __forceinline__ float bf2f(unsigned short u) {
    unsigned int v = (unsigned int)u << 16;
    return __builtin_bit_cast(float, v);
}

// sum of 4 sigmoids 1/(1+eq_d*ek_d) with one reciprocal
__device__ __forceinline__ float sig4(const f32x4 eq, const f32x4 ek) {
    float A = __builtin_fmaf(eq[0], ek[0], 1.0f);
    float B = __builtin_fmaf(eq[1], ek[1], 1.0f);
    float C = __builtin_fmaf(eq[2], ek[2], 1.0f);
    float D = __builtin_fmaf(eq[3], ek[3], 1.0f);
    float AB = A*B, CD = C*D;
    float num = __builtin_fmaf(A+B, CD, (C+D)*AB);
    return num * fast_rcp(AB*CD);
}

// ---------------------------------------------------------------------------
// K1: projections + hi/lo bf16 splits. 1024 blocks x 256, 4 rows/block.
// Outputs (all [B,S,64] unless noted): qh/ql, kh/kl (k incl. +bk), xh/xlo
// (bf16 hi/lo pairs), exf = exp(2x) f32, xT/vT bf16 [B,64,S] (PV B-frags).
// ---------------------------------------------------------------------------
__global__ __launch_bounds__(256) void k_proj(
    const float* __restrict__ x, const float* __restrict__ Wq,
    const float* __restrict__ Wk, const float* __restrict__ bkv,
    const float* __restrict__ Wv,
    unsigned short* __restrict__ qh, unsigned short* __restrict__ ql,
    unsigned short* __restrict__ kh, unsigned short* __restrict__ kl,
    unsigned short* __restrict__ xh, unsigned short* __restrict__ xlo,
    float* __restrict__ exf,
    unsigned short* __restrict__ xT, unsigned short* __restrict__ vT)
{
    __shared__ float xsh[4*68];
    const int t = threadIdx.x;
    const int r = t & 3, cc = t >> 2;
    const int row0 = blockIdx.x * 4;
    if (t < 64) {
        const int rr = t >> 4, seg = (t & 15) * 4;
        *(f32x4*)(xsh + rr*68 + seg) =
            *(const f32x4*)(x + (size_t)(row0 + rr)*64 + seg);
    }
    __syncthreads();

    const float* wqp = Wq + cc*64;
    const float* wkp = Wk + cc*64;
    const float* wvp = Wv + cc*64;
    float aq = 0.f, ak = 0.f, av = 0.f;
    #pragma unroll 4
    for (int e0 = 0; e0 < 64; e0 += 4) {
        f32x4 xv = *(const f32x4*)(xsh + r*68 + e0);
        f32x4 q4 = *(const f32x4*)(wqp + e0);
        f32x4 k4 = *(const f32x4*)(wkp + e0);
        f32x4 v4 = *(const f32x4*)(wvp + e0);
        #pragma unroll
        for (int u = 0; u < 4; ++u) {
            aq = __builtin_fmaf(xv[u], q4[u], aq);
            ak = __builtin_fmaf(xv[u], k4[u], ak);
            av = __builtin_fmaf(xv[u], v4[u], av);
        }
    }
    const int row = row0 + r;
    const int b = row >> 10, srow = row & 1023;
    const float C2 = 2.8853900817779268f;   // 2*log2(e)
    ak += bkv[cc];
    const size_t idx = (size_t)row*64 + cc;
    unsigned short h;
    h = f2bf(aq); qh[idx] = h; ql[idx] = f2bf(aq - bf2f(h));
    h = f2bf(ak); kh[idx] = h; kl[idx] = f2bf(ak - bf2f(h));
    const float xv_ = xsh[r*68 + cc];
    h = f2bf(xv_); xh[idx] = h; xlo[idx] = f2bf(xv_ - bf2f(h));
    exf[idx] = fast_exp2(C2 * xv_);
    xT[((size_t)b*64 + cc)*1024 + srow] = h;
    vT[((size_t)b*64 + cc)*1024 + srow] = f2bf(av);
}

// ---------------------------------------------------------------------------
// K2: fused scores+softmax+PV for all 3 branches. grid 1536 x 256.
//  bx <  512 : branch 3 (VALU sigmoid-sum), QBLK=32, 4-way k-split.
//  bx >= 512 : branches 1,2 (split-bf16 MFMA scores), QBLK=16, 2-way split.
// Fixed exp shifts (shift-invariant after l-division): br0 e^{s-64},
// br1 e^{s}, br3 e^{s3-32}. Writes unnormalized (acc, l) to po/lb slots:
// br0->0+split, br1->2+split, br3->4+s4.
// ---------------------------------------------------------------------------
__global__ __launch_bounds__(256) void k_fused(
    const unsigned short* __restrict__ xh, const unsigned short* __restrict__ xlo,
    const unsigned short* __restrict__ qh, const unsigned short* __restrict__ ql,
    const unsigned short* __restrict__ kh, const unsigned short* __restrict__ kl,
    const float* __restrict__ exf,
    const unsigned short* __restrict__ xT, const unsigned short* __restrict__ vT,
    const float* __restrict__ attn_scale,
    float* __restrict__ po, float* __restrict__ lb)
{
    __shared__ float sexq[32*68];
    __shared__ float sexk[64*68];
    __shared__ unsigned short Pl[32*72];
    __shared__ float lpart[4][16];
    __shared__ float l_arr[32];

    const int t = threadIdx.x;
    const int bx = blockIdx.x;
    const int lane = t & 63, wv = t >> 6;
    const int l15 = lane & 15, g = lane >> 4;
    const float LOG2E = 1.4426950408889634f;

    if (bx < 512) {
        // ================= branch 3 =================
        const int s4 = bx & 3, b = (bx >> 2) & 3;
        const int qt3 = 31 - (bx >> 4);
        const int q0 = qt3 * 32;
        const int nc = (qt3 >> 1) + 1;

        {   // stage sexq [32][68]
            const int rw = t >> 3, seg = (t & 7) * 8;
            const float* gsrc = exf + ((size_t)b*SS + q0 + rw)*64 + seg;
            f32x4* dst = (f32x4*)(sexq + rw*68 + seg);
            dst[0] = ((const f32x4*)gsrc)[0];
            dst[1] = ((const f32x4*)gsrc)[1];
        }
        __syncthreads();

        const int qp = t >> 4, kb = t & 15;     // rows qp*2+{0,1}, cols kb+16j
        const int qh_w = wv & 1, dbase = (wv >> 1) * 32;
        float lacc0 = 0.f, lacc1 = 0.f;
        f32x4 oacc0 = {0,0,0,0}, oacc1 = {0,0,0,0};

        for (int c = s4; c < nc; c += 4) {
            const int kc = c * 64;
            {   // stage sexk [64][68]
                const int rw = t >> 2, seg = (t & 3) * 16;
                const float* gsrc = exf + ((size_t)b*SS + kc + rw)*64 + seg;
                f32x4* dst = (f32x4*)(sexk + rw*68 + seg);
                #pragma unroll
                for (int i = 0; i < 4; ++i) dst[i] = ((const f32x4*)gsrc)[i];
            }
            __syncthreads();

            float ar0[4] = {0.f,0.f,0.f,0.f};
            float ar1[4] = {0.f,0.f,0.f,0.f};
            #pragma unroll 4
            for (int d0 = 0; d0 < 64; d0 += 4) {
                f32x4 eq0 = *(const f32x4*)(sexq + (qp*2+0)*68 + d0);
                f32x4 eq1 = *(const f32x4*)(sexq + (qp*2+1)*68 + d0);
                #pragma unroll
                for (int j = 0; j < 4; ++j) {
                    f32x4 ek = *(const f32x4*)(sexk + (kb + 16*j)*68 + d0);
                    ar0[j] += sig4(eq0, ek);
                    ar1[j] += sig4(eq1, ek);
                }
            }
            // p = e^{s3-32} = exp2(fma(ar, -2*log2e, 32*log2e)), masked
            #pragma unroll
            for (int j = 0; j < 4; ++j) {
                const int kg = kc + kb + 16*j;
                float e0 = (kg <= q0 + qp*2 + 0)
                    ? fast_exp2(__builtin_fmaf(ar0[j], -2.8853900817779268f, 46.166241308446475f)) : 0.f;
                float e1 = (kg <= q0 + qp*2 + 1)
                    ? fast_exp2(__builtin_fmaf(ar1[j], -2.8853900817779268f, 46.166241308446475f)) : 0.f;
                lacc0 += e0; lacc1 += e1;
                Pl[(qp*2+0)*72 + kb + 16*j] = f2bf(e0);
                Pl[(qp*2+1)*72 + kb + 16*j] = f2bf(e1);
            }
            __syncthreads();
            // PV: wave -> (qh_w, dbase); V B-frags direct from global xT
            const unsigned short* vb = xT + (size_t)b*64*1024;
            #pragma unroll
            for (int ks = 0; ks < 2; ++ks) {
                bf16x8 af = *(const bf16x8*)(Pl + (qh_w*16 + l15)*72 + ks*32 + g*8);
                bf16x8 b0 = *(const bf16x8*)(vb + (size_t)(dbase + l15)*1024 + kc + ks*32 + g*8);
                bf16x8 b1 = *(const bf16x8*)(vb + (size_t)(dbase + 16 + l15)*1024 + kc + ks*32 + g*8);
                oacc0 = __builtin_amdgcn_mfma_f32_16x16x32_bf16(af, b0, oacc0, 0, 0, 0);
                oacc1 = __builtin_amdgcn_mfma_f32_16x16x32_bf16(af, b1, oacc1, 0, 0, 0);
            }
            __syncthreads();
        }
        // row sums: reduce over kb within each 16-lane group
        #pragma unroll
        for (int off = 8; off >= 1; off >>= 1) {
            lacc0 += __shfl_xor(lacc0, off, 64);
            lacc1 += __shfl_xor(lacc1, off, 64);
        }
        if (kb == 0) { l_arr[qp*2] = lacc0; l_arr[qp*2+1] = lacc1; }
        __syncthreads();
        const size_t slot = 4 + s4;
        if (t < 32) lb[slot*((size_t)BB*SS) + (size_t)b*SS + q0 + t] = l_arr[t];
        float* pob = po + slot*((size_t)NSD) + ((size_t)b*SS + q0)*64;
        #pragma unroll
        for (int i = 0; i < 4; ++i) {
            const int rr = qh_w*16 + g*4 + i;
            pob[(size_t)rr*64 + dbase + l15]      = oacc0[i];
            pob[(size_t)rr*64 + dbase + 16 + l15] = oacc1[i];
        }
    } else {
        // ================= branches 1,2 =================
        const int y = bx - 512;
        const int split = y & 1, b = (y >> 1) & 3;
        const int qt = 63 - ((y >> 3) & 63);
        const int br = (y >> 9) & 1;
        const int q0 = qt * 16;
        const int nc = (qt >> 2) + 1;

        const unsigned short* Ah_p = (br ? qh : xh) + ((size_t)b*SS + q0)*64;
        const unsigned short* Al_p = (br ? ql : xlo) + ((size_t)b*SS + q0)*64;
        const unsigned short* Bh_p = (br ? kh : xh) + (size_t)b*SS*64;
        const unsigned short* Bl_p = (br ? kl : xlo) + (size_t)b*SS*64;
        const unsigned short* Vb   = (br ? vT : xT) + (size_t)b*64*1024;

        // A fragments (q-side, 2 k-steps, hi/lo) — loaded once
        const int ko = g * 8;
        bf16x8 Ah0 = *(const bf16x8*)(Ah_p + (size_t)l15*64 + ko);
        bf16x8 Ah1 = *(const bf16x8*)(Ah_p + (size_t)l15*64 + 32 + ko);
        bf16x8 Al0 = *(const bf16x8*)(Al_p + (size_t)l15*64 + ko);
        bf16x8 Al1 = *(const bf16x8*)(Al_p + (size_t)l15*64 + 32 + ko);

        const float pscale = br ? (0.125f * attn_scale[0] * LOG2E) : LOG2E;
        const float pshift = br ? 0.f : (-64.f * LOG2E);

        f32x4 lacc = {0,0,0,0};
        f32x4 oacc = {0,0,0,0};

        for (int c = split; c < nc; c += 2) {
            const int kc = c * 64;
            const int krow = kc + wv*16 + l15;
            bf16x8 Bh0 = *(const bf16x8*)(Bh_p + (size_t)krow*64 + ko);
            bf16x8 Bh1 = *(const bf16x8*)(Bh_p + (size_t)krow*64 + 32 + ko);
            bf16x8 Bl0 = *(const bf16x8*)(Bl_p + (size_t)krow*64 + ko);
            bf16x8 Bl1 = *(const bf16x8*)(Bl_p + (size_t)krow*64 + 32 + ko);
            f32x4 s = {0,0,0,0};
            s = __builtin_amdgcn_mfma_f32_16x16x32_bf16(Ah0, Bh0, s, 0, 0, 0);
            s = __builtin_amdgcn_mfma_f32_16x16x32_bf16(Ah1, Bh1, s, 0, 0, 0);
            s = __builtin_amdgcn_mfma_f32_16x16x32_bf16(Ah0, Bl0, s, 0, 0, 0);
            s = __builtin_amdgcn_mfma_f32_16x16x32_bf16(Ah1, Bl1, s, 0, 0, 0);
            s = __builtin_amdgcn_mfma_f32_16x16x32_bf16(Al0, Bh0, s, 0, 0, 0);
            s = __builtin_amdgcn_mfma_f32_16x16x32_bf16(Al1, Bh1, s, 0, 0, 0);
            // exp+mask in C-layout (col=lane&15=k-local, row=g*4+i=q-local)
            const int kg = kc + wv*16 + l15;
            #pragma unroll
            for (int i = 0; i < 4; ++i) {
                const int q = q0 + g*4 + i;
                float e = (kg <= q) ? fast_exp2(__builtin_fmaf(s[i], pscale, pshift)) : 0.f;
                lacc[i] += e;
                Pl[(g*4+i)*72 + wv*16 + l15] = f2bf(e);
            }
            __syncthreads();
            // PV: wave wv -> d-strip wv*16
            #pragma unroll
            for (int ks = 0; ks < 2; ++ks) {
                bf16x8 af = *(const bf16x8*)(Pl + l15*72 + ks*32 + g*8);
                bf16x8 bf_ = *(const bf16x8*)(Vb + (size_t)(wv*16 + l15)*1024 + kc + ks*32 + g*8);
                oacc = __builtin_amdgcn_mfma_f32_16x16x32_bf16(af, bf_, oacc, 0, 0, 0);
            }
            __syncthreads();
        }
        // l: reduce over cols (lanes of 16-group), then across waves (strips)
        #pragma unroll
        for (int off = 8; off >= 1; off >>= 1) {
            lacc[0] += __shfl_xor(lacc[0], off, 64);
            lacc[1] += __shfl_xor(lacc[1], off, 64);
            lacc[2] += __shfl_xor(lacc[2], off, 64);
            lacc[3] += __shfl_xor(lacc[3], off, 64);
        }
        if (l15 == 0) {
            #pragma unroll
            for (int i = 0; i < 4; ++i) lpart[wv][g*4 + i] = lacc[i];
        }
        __syncthreads();
        const size_t slot = (size_t)(br*2 + split);
        if (t < 16) {
            float l = lpart[0][t] + lpart[1][t] + lpart[2][t] + lpart[3][t];
            lb[slot*((size_t)BB*SS) + (size_t)b*SS + q0 + t] = l;
        }
        float* pob = po + slot*((size_t)NSD) + ((size_t)b*SS + q0)*64;
        #pragma unroll
        for (int i = 0; i < 4; ++i)
            pob[(size_t)(g*4 + i)*64 + wv*16 + l15] = oacc[i];
    }
}

// ---------------------------------------------------------------------------
// K3: out = w0*(p0+p1)/(l0+l1) + w1*(p2+p3)/(l2+l3) + w2*(p4..7)/(l4..7)
// ---------------------------------------------------------------------------
__global__ __launch_bounds__(256) void k_comb(
    const float* __restrict__ po, const float* __restrict__ lb,
    const float* __restrict__ attn_w, float* __restrict__ out)
{
    const int v = blockIdx.x*256 + threadIdx.x;      // f32x4 index over [B,S,D]
    const int qg = v >> 4;                           // global row b*S+q
    const float aw0 = attn_w[0], aw1 = attn_w[1], aw2 = attn_w[2];
    const float iws = fast_rcp(aw0 + aw1 + aw2);
    const f32x4* p = (const f32x4*)po;
    const int NQ = BB*SS;

    f32x4 s01 = p[(size_t)0*65536 + v] + p[(size_t)1*65536 + v];
    f32x4 s23 = p[(size_t)2*65536 + v] + p[(size_t)3*65536 + v];
    f32x4 s47 = (p[(size_t)4*65536 + v] + p[(size_t)5*65536 + v])
              + (p[(size_t)6*65536 + v] + p[(size_t)7*65536 + v]);
    const float f0 = aw0 * iws * fast_rcp(lb[0*NQ + qg] + lb[1*NQ + qg]);
    const float f1 = aw1 * iws * fast_rcp(lb[2*NQ + qg] + lb[3*NQ + qg]);
    const float f2 = aw2 * iws * fast_rcp(lb[4*NQ + qg] + lb[5*NQ + qg]
                                        + lb[6*NQ + qg] + lb[7*NQ + qg]);
    f32x4 o;
    #pragma unroll
    for (int u = 0; u < 4; ++u)
        o[u] = __builtin_fmaf(s01[u], f0,
               __builtin_fmaf(s23[u], f1, s47[u]*f2));
    ((f32x4*)out)[v] = o;
}

extern "C" void kernel_launch(void* const* d_in, const int* in_sizes, int n_in,
                              void* d_out, int out_size, void* d_ws, size_t ws_size,
                              hipStream_t stream) {
    (void)in_sizes; (void)n_in; (void)out_size; (void)ws_size;
    const float* x          = (const float*)d_in[0];
    const float* Wq         = (const float*)d_in[1];
    const float* Wk         = (const float*)d_in[2];
    const float* bk         = (const float*)d_in[3];
    const float* Wv         = (const float*)d_in[4];
    const float* attn_w     = (const float*)d_in[5];
    const float* attn_scale = (const float*)d_in[6];
    float* out              = (float*)d_out;

    // workspace carve-up (~13.5 MB)
    float* exf = (float*)d_ws;                            // [B,S,64] f32
    unsigned short* qh  = (unsigned short*)(exf + NSD);   // 6 bf16 [B,S,64]
    unsigned short* ql  = qh  + NSD;
    unsigned short* kh  = ql  + NSD;
    unsigned short* kl  = kh  + NSD;
    unsigned short* xh  = kl  + NSD;
    unsigned short* xlo = xh  + NSD;
    unsigned short* xT  = xlo + NSD;                      // bf16 [B,64,S]
    unsigned short* vT  = xT  + NSD;
    float* po = (float*)(vT + NSD);                       // [8][B,S,64] f32
    float* lb = po + (size_t)8*NSD;                       // [8][B*S]

    k_proj <<<1024, 256, 0, stream>>>(x, Wq, Wk, bk, Wv,
                                      qh, ql, kh, kl, xh, xlo, exf, xT, vT);
    k_fused<<<1536, 256, 0, stream>>>(xh, xlo, qh, ql, kh, kl, exf, xT, vT,
                                      attn_scale, po, lb);
    k_comb <<<256, 256, 0, stream>>>(po, lb, attn_w, out);
}